// Round 1
// baseline (142.338 us; speedup 1.0000x reference)
//
#include <hip/hip_runtime.h>
#include <math.h>

// NLM denoise: x [2,3,512,512] f32, SWS=11 (121 shifts), TWS=5, circular wrap.
// y = luminance(clip(x)); d2(p,s) = sum_{5x5 t} (y[p+t]-y[p+t-s])^2
// w = exp(-sqrt(d2)/3); out_c = clip( sum_s w*x_c[p-s] / sum_s w , 0, 1)

#define H_IMG 512
#define W_IMG 512
#define MASK  511
#define HWSZ  (H_IMG * W_IMG)
#define TILE  32
#define YHALO 7
#define XHALO 5
#define YDIM  (TILE + 2 * YHALO)   // 46
#define YSTR  48                   // padded row stride for y LDS
#define XDIM  (TILE + 2 * XHALO)   // 42

__global__ __launch_bounds__(256, 2)
void nlm_kernel(const float* __restrict__ x, float* __restrict__ out) {
    __shared__ float  ldsY[YDIM * YSTR];        // 46*48*4  = 8.8 KB
    __shared__ float4 ldsX[XDIM * XDIM];        // 42*42*16 = 28.2 KB

    const int n  = blockIdx.z;
    const int ti = blockIdx.y * TILE;           // tile row origin (abs)
    const int tj = blockIdx.x * TILE;           // tile col origin (abs)
    const int tx = threadIdx.x;                 // 0..31
    const int ty = threadIdx.y;                 // 0..7
    const int tid = ty * 32 + tx;

    const float* xb = x + (size_t)n * 3 * HWSZ;

    // ---- stage y (luminance of clipped x), tile + halo 7 ----
    for (int e = tid; e < YDIM * YDIM; e += 256) {
        int ry = e / YDIM, rc = e - ry * YDIM;
        int gi = (ti + ry - YHALO) & MASK;
        int gj = (tj + rc - YHALO) & MASK;
        size_t o = (size_t)gi * W_IMG + gj;
        float r = fminf(fmaxf(xb[o],            0.f), 1.f);
        float g = fminf(fmaxf(xb[o + HWSZ],     0.f), 1.f);
        float b = fminf(fmaxf(xb[o + 2 * HWSZ], 0.f), 1.f);
        ldsY[ry * YSTR + rc] = 0.299f * r + 0.587f * g + 0.114f * b;
    }
    // ---- stage x (raw), tile + halo 5, packed float4 ----
    for (int e = tid; e < XDIM * XDIM; e += 256) {
        int ry = e / XDIM, rc = e - ry * XDIM;
        int gi = (ti + ry - XHALO) & MASK;
        int gj = (tj + rc - XHALO) & MASK;
        size_t o = (size_t)gi * W_IMG + gj;
        ldsX[e] = make_float4(xb[o], xb[o + HWSZ], xb[o + 2 * HWSZ], 0.f);
    }
    __syncthreads();

    const int jl = tx + YHALO;        // y-LDS col of this thread's column
    const int il = ty * 4 + YHALO;    // y-LDS row of first of 4 outputs

    // center y patch in registers: rows il-2..il+5, cols jl-2..jl+2
    float cy[8][5];
    #pragma unroll
    for (int t = 0; t < 8; ++t)
        #pragma unroll
        for (int c = 0; c < 5; ++c)
            cy[t][c] = ldsY[(il - 2 + t) * YSTR + (jl - 2 + c)];

    float den[4]  = {0.f, 0.f, 0.f, 0.f};
    float num0[4] = {0.f, 0.f, 0.f, 0.f};
    float num1[4] = {0.f, 0.f, 0.f, 0.f};
    float num2[4] = {0.f, 0.f, 0.f, 0.f};

    for (int xs = -5; xs <= 5; ++xs) {
        const int jc  = jl - xs - 2;        // y-LDS col base of shifted 5-window
        const int xjc = tx + XHALO - xs;    // x-LDS col of shifted neighbor

        float  sw[8][5];   // rolling shifted-y window (ring over rows)
        float4 xw[4];      // rolling x neighbors (ring over rows)

        #pragma unroll
        for (int k = 0; k <= 10; ++k) {     // ys = 5 - k
            if (k == 0) {
                #pragma unroll
                for (int t = 0; t < 8; ++t)
                    #pragma unroll
                    for (int c = 0; c < 5; ++c)
                        sw[t][c] = ldsY[(il - 7 + t) * YSTR + jc + c];
                #pragma unroll
                for (int t = 0; t < 4; ++t)
                    xw[t] = ldsX[(ty * 4 + t) * XDIM + xjc];
            } else {
                #pragma unroll
                for (int c = 0; c < 5; ++c)
                    sw[(k + 7) & 7][c] = ldsY[(il + k) * YSTR + jc + c];
                xw[(k + 3) & 3] = ldsX[(ty * 4 + k + 3) * XDIM + xjc];
            }

            // row sums of squared diffs: h[t] for center rows il-2+t
            float h[8];
            #pragma unroll
            for (int t = 0; t < 8; ++t) {
                float s = 0.f;
                #pragma unroll
                for (int c = 0; c < 5; ++c) {
                    float d = cy[t][c] - sw[(k + t) & 7][c];
                    s = fmaf(d, d, s);
                }
                h[t] = s;
            }

            float d2 = h[0] + h[1] + h[2] + h[3] + h[4];
            #pragma unroll
            for (int o = 0; o < 4; ++o) {
                if (o > 0) d2 += h[o + 4] - h[o - 1];
                float w = __expf(-sqrtf(d2) * (1.0f / 3.0f));
                float4 xv = xw[(k + o) & 3];
                num0[o] = fmaf(w, xv.x, num0[o]);
                num1[o] = fmaf(w, xv.y, num1[o]);
                num2[o] = fmaf(w, xv.z, num2[o]);
                den[o] += w;
            }
        }
    }

    // ---- epilogue ----
    float* ob = out + (size_t)n * 3 * HWSZ;
    #pragma unroll
    for (int o = 0; o < 4; ++o) {
        int gi = ti + ty * 4 + o;
        int gj = tj + tx;
        size_t off = (size_t)gi * W_IMG + gj;
        float inv = 1.0f / den[o];
        float v0 = fminf(fmaxf(num0[o] * inv, 0.f), 1.f);
        float v1 = fminf(fmaxf(num1[o] * inv, 0.f), 1.f);
        float v2 = fminf(fmaxf(num2[o] * inv, 0.f), 1.f);
        ob[off]            = v0;
        ob[off + HWSZ]     = v1;
        ob[off + 2 * HWSZ] = v2;
    }
}

extern "C" void kernel_launch(void* const* d_in, const int* in_sizes, int n_in,
                              void* d_out, int out_size, void* d_ws, size_t ws_size,
                              hipStream_t stream) {
    const float* x = (const float*)d_in[0];
    float* out = (float*)d_out;
    dim3 grid(W_IMG / TILE, H_IMG / TILE, 2);   // (16,16,2)
    dim3 block(32, 8);
    nlm_kernel<<<grid, block, 0, stream>>>(x, out);
}

// Round 3
// 114.381 us; speedup vs baseline: 1.2444x; 1.2444x over previous
//
#include <hip/hip_runtime.h>
#include <math.h>

// NLM denoise: x [2,3,512,512] f32, SWS=11 (121 shifts), TWS=5, circular wrap.
// d2(p,s) = ||Pc||^2 + ||Ps||^2 - 2<Pc,Ps>  (patch-norm table + cross-corr)
// w = exp(-sqrt(d2)/3); out_c = clip( sum_s w*x_c[p-s] / sum_s w , 0, 1)

#define H_IMG 512
#define W_IMG 512
#define MASK  511
#define HWSZ  (H_IMG * W_IMG)
#define TILE  32
#define HALO  7
#define XD    46          // TILE + 2*HALO
#define YSTR  48          // padded stride for y LDS
#define HSTR  44          // stride for Hrow LDS (42 cols used)

__global__ __launch_bounds__(256, 2)
void nlm_kernel(const float* __restrict__ x, float* __restrict__ out) {
    __shared__ float4 ldsX[XD * XD];       // 33856 B
    __shared__ float  ldsY[XD * YSTR];     //  8832 B
    __shared__ float  ldsH[XD * HSTR];     //  8096 B   (total 50784 B)

    const int n  = blockIdx.z;
    const int ti = blockIdx.y * TILE;
    const int tj = blockIdx.x * TILE;
    const int tx = threadIdx.x;            // 0..31
    const int ty = threadIdx.y;            // 0..7
    const int tid = ty * 32 + tx;

    const float* xb = x + (size_t)n * 3 * HWSZ;

    // ---- stage x (tile + halo 7), packed float4 ----
    for (int e = tid; e < XD * XD; e += 256) {
        int r = e / XD, c = e - r * XD;
        int gi = (ti + r - HALO) & MASK;
        int gj = (tj + c - HALO) & MASK;
        size_t o = (size_t)gi * W_IMG + gj;
        ldsX[e] = make_float4(xb[o], xb[o + HWSZ], xb[o + 2 * HWSZ], 0.f);
    }
    __syncthreads();

    // ---- luminance from staged x ----
    for (int e = tid; e < XD * XD; e += 256) {
        float4 v = ldsX[e];
        float r = fminf(fmaxf(v.x, 0.f), 1.f);
        float g = fminf(fmaxf(v.y, 0.f), 1.f);
        float b = fminf(fmaxf(v.z, 0.f), 1.f);
        int rr = e / XD, cc = e - rr * XD;
        ldsY[rr * YSTR + cc] = 0.299f * r + 0.587f * g + 0.114f * b;
    }
    __syncthreads();

    // ---- Hrow(r,c) = sum_{d=0..4} y(r,c+d)^2  (horizontal 5-box of y^2) ----
    for (int e = tid; e < XD * 42; e += 256) {
        int r = e / 42, c = e - r * 42;
        const float* yr = &ldsY[r * YSTR + c];
        float a0 = yr[0], a1 = yr[1], a2 = yr[2], a3 = yr[3], a4 = yr[4];
        ldsH[r * HSTR + c] = a0*a0 + a1*a1 + a2*a2 + a3*a3 + a4*a4;
    }
    __syncthreads();

    const int jl = tx + HALO;          // LDS col of this thread's column
    const int il = ty * 4 + HALO;      // LDS row of first of 4 outputs

    // center patch rows in registers + their norms
    float cy[8][5];
    float hc[8];
    #pragma unroll
    for (int t = 0; t < 8; ++t) {
        #pragma unroll
        for (int c = 0; c < 5; ++c)
            cy[t][c] = ldsY[(il - 2 + t) * YSTR + (jl - 2 + c)];
        hc[t] = ldsH[(il - 2 + t) * HSTR + (jl - 2)];
    }

    float den[4]  = {0.f, 0.f, 0.f, 0.f};
    float num0[4] = {0.f, 0.f, 0.f, 0.f};
    float num1[4] = {0.f, 0.f, 0.f, 0.f};
    float num2[4] = {0.f, 0.f, 0.f, 0.f};

    #pragma unroll 1
    for (int xs = -5; xs <= 5; ++xs) {
        const int jc  = jl - xs - 2;   // shifted 5-window base col
        const int xjc = jl - xs;       // shifted x neighbor col (LDSX)

        float  sw[8][5];               // shifted-y ring over rows
        float  Hs[8];                  // shifted-row-norm ring
        float4 xw[4];                  // x-neighbor ring

        #pragma unroll
        for (int t = 0; t < 8; ++t) {
            #pragma unroll
            for (int c = 0; c < 5; ++c)
                sw[t][c] = ldsY[(il - 7 + t) * YSTR + jc + c];
            Hs[t] = ldsH[(il - 7 + t) * HSTR + jc];
        }
        #pragma unroll
        for (int t = 0; t < 4; ++t)
            xw[t] = ldsX[(il - 5 + t) * XD + xjc];

        #pragma unroll
        for (int k = 0; k <= 10; ++k) {     // ys = 5 - k
            // prefetch next step's ring entries (covers LDS latency)
            float nsw[5], nHs;
            float4 nxw;
            if (k < 10) {
                const int nr = il + k + 1;
                #pragma unroll
                for (int c = 0; c < 5; ++c) nsw[c] = ldsY[nr * YSTR + jc + c];
                nHs = ldsH[nr * HSTR + jc];
                nxw = ldsX[(il + k - 1) * XD + xjc];
            }

            // row-pair distances via cross-correlation
            float h[8];
            #pragma unroll
            for (int t = 0; t < 8; ++t) {
                const int m = (t + k) & 7;
                float s = 0.f;
                #pragma unroll
                for (int c = 0; c < 5; ++c)
                    s = fmaf(cy[t][c], sw[m][c], s);
                h[t] = fmaf(-2.f, s, hc[t] + Hs[m]);
            }

            float d2 = h[0] + h[1] + h[2] + h[3] + h[4];
            #pragma unroll
            for (int o = 0; o < 4; ++o) {
                if (o > 0) d2 += h[o + 4] - h[o - 1];
                float d2c = fmaxf(d2, 0.f);                  // cancellation guard
                float w = __expf(__builtin_amdgcn_sqrtf(d2c) * (-1.0f / 3.0f));
                float4 xv = xw[(k + o) & 3];
                num0[o] = fmaf(w, xv.x, num0[o]);
                num1[o] = fmaf(w, xv.y, num1[o]);
                num2[o] = fmaf(w, xv.z, num2[o]);
                den[o] += w;
            }

            // commit prefetched entries
            if (k < 10) {
                #pragma unroll
                for (int c = 0; c < 5; ++c) sw[k & 7][c] = nsw[c];
                Hs[k & 7] = nHs;
                xw[k & 3] = nxw;
            }
        }
    }

    // ---- epilogue ----
    float* ob = out + (size_t)n * 3 * HWSZ;
    #pragma unroll
    for (int o = 0; o < 4; ++o) {
        int gi = ti + ty * 4 + o;
        int gj = tj + tx;
        size_t off = (size_t)gi * W_IMG + gj;
        float inv = __builtin_amdgcn_rcpf(den[o]);
        float v0 = fminf(fmaxf(num0[o] * inv, 0.f), 1.f);
        float v1 = fminf(fmaxf(num1[o] * inv, 0.f), 1.f);
        float v2 = fminf(fmaxf(num2[o] * inv, 0.f), 1.f);
        ob[off]            = v0;
        ob[off + HWSZ]     = v1;
        ob[off + 2 * HWSZ] = v2;
    }
}

extern "C" void kernel_launch(void* const* d_in, const int* in_sizes, int n_in,
                              void* d_out, int out_size, void* d_ws, size_t ws_size,
                              hipStream_t stream) {
    const float* x = (const float*)d_in[0];
    float* out = (float*)d_out;
    dim3 grid(W_IMG / TILE, H_IMG / TILE, 2);   // (16,16,2) = 512 blocks
    dim3 block(32, 8);
    nlm_kernel<<<grid, block, 0, stream>>>(x, out);
}

// Round 4
// 100.847 us; speedup vs baseline: 1.4114x; 1.1342x over previous
//
#include <hip/hip_runtime.h>
#include <math.h>

// NLM denoise: x [2,3,512,512] f32, SWS=11 (121 shifts), TWS=5, circular wrap.
// d2(p,s) = ||Pc||^2 + ||Ps||^2 - 2<Pc,Ps>, cross-terms via v_dot2_f32_f16
// on f16-pair LDS table; norms via row-norm table + sliding vertical sums.
// w = exp2(-log2(e)/3 * sqrt(d2)); out_c = clip(sum w*x / sum w, 0, 1)

#define H_IMG 512
#define W_IMG 512
#define MASK  511
#define HWSZ  (H_IMG * W_IMG)
#define TILE  32
#define HALO  7
#define XD    46          // TILE + 2*HALO (rows; x/y tiles)
#define YSTR  48          // padded col-stride for yf / ldsY2
#define HSTR  44          // col-stride for ldsH (42 cols used)

typedef _Float16 h2 __attribute__((ext_vector_type(2)));

__device__ __forceinline__ float fdot2(h2 a, h2 b, float c) {
#if __has_builtin(__builtin_amdgcn_fdot2)
    return __builtin_amdgcn_fdot2(a, b, c, false);
#else
    return c + (float)a.x * (float)b.x + (float)a.y * (float)b.y;
#endif
}

__device__ __forceinline__ float fast_exp2(float x) {
#if __has_builtin(__builtin_amdgcn_exp2f)
    return __builtin_amdgcn_exp2f(x);
#else
    return __expf(x * 0.6931471805599453f);
#endif
}

__global__ __launch_bounds__(256, 4)
void nlm_kernel(const float* __restrict__ x, float* __restrict__ out) {
    __shared__ float4   ldsX[XD * XD];        // 33856 B
    __shared__ float    ldsYf[XD * YSTR];     //  8832 B (f32 y, 47 cols used)
    __shared__ unsigned ldsY2[XD * YSTR];     //  8832 B (f16 pair (y_c, y_{c+1}))
    __shared__ float    ldsH[XD * HSTR];      //  8096 B  -> total ~59.6 KB

    const int n  = blockIdx.z;
    const int ti = blockIdx.y * TILE;
    const int tj = blockIdx.x * TILE;
    const int tx = threadIdx.x;            // 0..31
    const int ty = threadIdx.y;            // 0..7
    const int tid = ty * 32 + tx;

    const float* xb = x + (size_t)n * 3 * HWSZ;

    // ---- A: stage x (tile + halo 7), packed float4 ----
    for (int e = tid; e < XD * XD; e += 256) {
        int r = e / XD, c = e - r * XD;
        int gi = (ti + r - HALO) & MASK;
        int gj = (tj + c - HALO) & MASK;
        size_t o = (size_t)gi * W_IMG + gj;
        ldsX[e] = make_float4(xb[o], xb[o + HWSZ], xb[o + 2 * HWSZ], 0.f);
    }
    __syncthreads();

    // ---- B: luminance (f32), 46 rows x 47 cols (col 46 dup of 45, masked later) ----
    for (int e = tid; e < XD * 47; e += 256) {
        int r = e / 47, c = e - r * 47;
        int cs = (c == 46) ? 45 : c;
        float4 v = ldsX[r * XD + cs];
        float rr = fminf(fmaxf(v.x, 0.f), 1.f);
        float gg = fminf(fmaxf(v.y, 0.f), 1.f);
        float bb = fminf(fmaxf(v.z, 0.f), 1.f);
        ldsYf[r * YSTR + c] = 0.299f * rr + 0.587f * gg + 0.114f * bb;
    }
    __syncthreads();

    // ---- C: f16 pair table: entry[r][c] = (y(c), y(c+1)) ----
    for (int e = tid; e < XD * XD; e += 256) {   // 46x46 entries
        int r = e / XD, c = e - r * XD;
        h2 p;
        p.x = (_Float16)ldsYf[r * YSTR + c];
        p.y = (_Float16)ldsYf[r * YSTR + c + 1];
        ldsY2[r * YSTR + c] = __builtin_bit_cast(unsigned, p);
    }
    __syncthreads();

    // ---- D: row-norm table H(r,c) = sum_{d=0..4} yh(r,c+d)^2 (from f16 values) ----
    for (int e = tid; e < XD * 42; e += 256) {
        int r = e / 42, c = e - r * 42;
        h2 a  = __builtin_bit_cast(h2, ldsY2[r * YSTR + c]);
        h2 b  = __builtin_bit_cast(h2, ldsY2[r * YSTR + c + 2]);
        h2 cc = __builtin_bit_cast(h2, ldsY2[r * YSTR + c + 4]);
        float x0 = (float)a.x, x1 = (float)a.y;
        float x2 = (float)b.x, x3 = (float)b.y;
        float x4 = (float)cc.x;
        ldsH[r * HSTR + c] = x0*x0 + x1*x1 + x2*x2 + x3*x3 + x4*x4;
    }
    __syncthreads();

    const int jl = tx + HALO;          // LDS col of this thread's column
    const int il = ty * 4 + HALO;      // LDS row of first of 4 outputs

    // center patch as f16 pairs (pairing (c0,c1),(c2,c3),(c4,0)) + Vc sums
    h2 cyP[8][3];
    float Vc[4];
    {
        float hcv[8];
        #pragma unroll
        for (int t = 0; t < 8; ++t) {
            int base = (il - 2 + t) * YSTR + (jl - 2);
            cyP[t][0] = __builtin_bit_cast(h2, ldsY2[base]);
            cyP[t][1] = __builtin_bit_cast(h2, ldsY2[base + 2]);
            h2 z = __builtin_bit_cast(h2, ldsY2[base + 4]);
            z.y = (_Float16)0.f;
            cyP[t][2] = z;
            hcv[t] = ldsH[(il - 2 + t) * HSTR + (jl - 2)];
        }
        Vc[0] = ((hcv[0] + hcv[1]) + (hcv[2] + hcv[3])) + hcv[4];
        Vc[1] = Vc[0] - hcv[0] + hcv[5];
        Vc[2] = Vc[1] - hcv[1] + hcv[6];
        Vc[3] = Vc[2] - hcv[2] + hcv[7];
    }

    float den[4]  = {0.f, 0.f, 0.f, 0.f};
    float num0[4] = {0.f, 0.f, 0.f, 0.f};
    float num1[4] = {0.f, 0.f, 0.f, 0.f};
    float num2[4] = {0.f, 0.f, 0.f, 0.f};

    const float KEXP = -0.48089834696298783f;   // -log2(e)/3

    #pragma unroll 1
    for (int xs = -5; xs <= 5; ++xs) {
        const int jc  = jl - xs - 2;   // shifted 5-window base col
        const int xjc = jl - xs;       // shifted x neighbor col (ldsX)

        h2     swP[8][3];              // shifted-y f16-pair ring over rows
        float  Hs[8];                  // shifted row-norm ring
        float4 xw[4];                  // x-neighbor ring

        #pragma unroll
        for (int t = 0; t < 8; ++t) {
            int base = (il - 7 + t) * YSTR + jc;
            swP[t][0] = __builtin_bit_cast(h2, ldsY2[base]);
            swP[t][1] = __builtin_bit_cast(h2, ldsY2[base + 2]);
            swP[t][2] = __builtin_bit_cast(h2, ldsY2[base + 4]);
            Hs[t] = ldsH[(il - 7 + t) * HSTR + jc];
        }
        #pragma unroll
        for (int t = 0; t < 4; ++t)
            xw[t] = ldsX[(il - 5 + t) * XD + xjc];

        float W0p = 0.f, HsOld = 0.f;

        #pragma unroll
        for (int k = 0; k <= 10; ++k) {     // ys = 5 - k
            // prefetch next step's ring entries
            h2 nsw0, nsw1, nsw2; float nHs; float4 nxw;
            if (k < 10) {
                const int nr = il + k + 1;
                int base = nr * YSTR + jc;
                nsw0 = __builtin_bit_cast(h2, ldsY2[base]);
                nsw1 = __builtin_bit_cast(h2, ldsY2[base + 2]);
                nsw2 = __builtin_bit_cast(h2, ldsY2[base + 4]);
                nHs  = ldsH[nr * HSTR + jc];
                nxw  = ldsX[(il + k - 1) * XD + xjc];
            }

            // row-dot cross terms (f16 MACs, f32 accumulate)
            float s[8];
            #pragma unroll
            for (int t = 0; t < 8; ++t) {
                const int m = (t + k) & 7;
                s[t] = fdot2(cyP[t][0], swP[m][0],
                       fdot2(cyP[t][1], swP[m][1],
                       fdot2(cyP[t][2], swP[m][2], 0.f)));
            }

            // sliding 5-row sums of cross terms
            float S0 = ((s[0] + s[1]) + (s[2] + s[3])) + s[4];
            float S1 = S0 - s[0] + s[5];
            float S2 = S1 - s[1] + s[6];
            float S3 = S2 - s[2] + s[7];

            // sliding 5-row sums of shifted norms
            float W0;
            if (k == 0) W0 = ((Hs[0] + Hs[1]) + (Hs[2] + Hs[3])) + Hs[4];
            else        W0 = W0p - HsOld + Hs[(k + 4) & 7];
            float W1 = W0 - Hs[k & 7]       + Hs[(k + 5) & 7];
            float W2 = W1 - Hs[(k + 1) & 7] + Hs[(k + 6) & 7];
            float W3 = W2 - Hs[(k + 2) & 7] + Hs[(k + 7) & 7];
            W0p = W0;

            float d2a[4];
            d2a[0] = fmaf(-2.f, S0, Vc[0] + W0);
            d2a[1] = fmaf(-2.f, S1, Vc[1] + W1);
            d2a[2] = fmaf(-2.f, S2, Vc[2] + W2);
            d2a[3] = fmaf(-2.f, S3, Vc[3] + W3);

            #pragma unroll
            for (int o = 0; o < 4; ++o) {
                float sd = __builtin_amdgcn_sqrtf(__builtin_fabsf(d2a[o]));
                float w  = fast_exp2(KEXP * sd);
                float4 xv = xw[(k + o) & 3];
                num0[o] = fmaf(w, xv.x, num0[o]);
                num1[o] = fmaf(w, xv.y, num1[o]);
                num2[o] = fmaf(w, xv.z, num2[o]);
                den[o] += w;
            }

            // commit prefetched ring entries
            if (k < 10) {
                swP[k & 7][0] = nsw0;
                swP[k & 7][1] = nsw1;
                swP[k & 7][2] = nsw2;
                HsOld = Hs[k & 7];
                Hs[k & 7] = nHs;
                xw[k & 3] = nxw;
            }
        }
    }

    // ---- epilogue ----
    float* ob = out + (size_t)n * 3 * HWSZ;
    #pragma unroll
    for (int o = 0; o < 4; ++o) {
        int gi = ti + ty * 4 + o;
        int gj = tj + tx;
        size_t off = (size_t)gi * W_IMG + gj;
        float inv = __builtin_amdgcn_rcpf(den[o]);
        float v0 = fminf(fmaxf(num0[o] * inv, 0.f), 1.f);
        float v1 = fminf(fmaxf(num1[o] * inv, 0.f), 1.f);
        float v2 = fminf(fmaxf(num2[o] * inv, 0.f), 1.f);
        ob[off]            = v0;
        ob[off + HWSZ]     = v1;
        ob[off + 2 * HWSZ] = v2;
    }
}

extern "C" void kernel_launch(void* const* d_in, const int* in_sizes, int n_in,
                              void* d_out, int out_size, void* d_ws, size_t ws_size,
                              hipStream_t stream) {
    const float* x = (const float*)d_in[0];
    float* out = (float*)d_out;
    dim3 grid(W_IMG / TILE, H_IMG / TILE, 2);   // (16,16,2) = 512 blocks
    dim3 block(32, 8);
    nlm_kernel<<<grid, block, 0, stream>>>(x, out);
}

// Round 5
// 98.976 us; speedup vs baseline: 1.4381x; 1.0189x over previous
//
#include <hip/hip_runtime.h>
#include <math.h>

// NLM denoise: x [2,3,512,512] f32, SWS=11 (121 shifts), TWS=5, circular wrap.
// d2 = ||Pc||^2 + ||Ps||^2 - 2<Pc,Ps>; cross-terms via v_dot2_f32_f16 on f16
// pair table; norms via PRECOMPUTED vertical 5-sum table V (K^2-prescaled).
// w = exp2(-sqrt(K2*d2)), K = log2(e)/3; out = clip(sum w*x / sum w, 0, 1)

#define H_IMG 512
#define W_IMG 512
#define MASK  511
#define HWSZ  (H_IMG * W_IMG)
#define TILE  32
#define HALO  7
#define XD    46          // TILE + 2*HALO
#define YSTR  48          // padded col-stride for yf / ldsY2
#define HSTR  44          // col-stride for ldsH (42 cols used)
#define VSTR  44          // col-stride for ldsV (42 cols used)

typedef _Float16 h2 __attribute__((ext_vector_type(2)));

__device__ __forceinline__ float fdot2(h2 a, h2 b, float c) {
#if __has_builtin(__builtin_amdgcn_fdot2)
    return __builtin_amdgcn_fdot2(a, b, c, false);
#else
    return c + (float)a.x * (float)b.x + (float)a.y * (float)b.y;
#endif
}

__device__ __forceinline__ float fast_exp2(float x) {
#if __has_builtin(__builtin_amdgcn_exp2f)
    return __builtin_amdgcn_exp2f(x);
#else
    return __expf(x * 0.6931471805599453f);
#endif
}

#define K2C   0.23126321070979063f    // (log2(e)/3)^2
#define N2K2 -0.46252642141958126f    // -2*K2C

__global__ __launch_bounds__(256, 4)
void nlm_kernel(const float* __restrict__ x, float* __restrict__ out) {
    __shared__ float4   ldsX[XD * XD];        // 33856 B
    __shared__ float    ldsYf[XD * YSTR];     //  8832 B (f32 y, 47 cols used)
    __shared__ unsigned ldsY2[XD * YSTR];     //  8832 B (f16 pair (y_c,y_{c+1}))
    __shared__ float    ldsH[XD * HSTR];      //  8096 B (row 5-norms)
    __shared__ float    ldsV[42 * VSTR];      //  7392 B (K2 * vertical 5-sum of H)
                                              //  total 67008 B -> 2 blocks/CU

    const int n  = blockIdx.z;
    const int ti = blockIdx.y * TILE;
    const int tj = blockIdx.x * TILE;
    const int tx = threadIdx.x;            // 0..31
    const int ty = threadIdx.y;            // 0..7
    const int tid = ty * 32 + tx;

    const float* xb = x + (size_t)n * 3 * HWSZ;

    // ---- A: stage x (tile + halo 7), packed float4 ----
    for (int e = tid; e < XD * XD; e += 256) {
        int r = e / XD, c = e - r * XD;
        int gi = (ti + r - HALO) & MASK;
        int gj = (tj + c - HALO) & MASK;
        size_t o = (size_t)gi * W_IMG + gj;
        ldsX[e] = make_float4(xb[o], xb[o + HWSZ], xb[o + 2 * HWSZ], 0.f);
    }
    __syncthreads();

    // ---- B: luminance (f32), 46 rows x 47 cols (col 46 dup, masked later) ----
    for (int e = tid; e < XD * 47; e += 256) {
        int r = e / 47, c = e - r * 47;
        int cs = (c == 46) ? 45 : c;
        float4 v = ldsX[r * XD + cs];
        float rr = fminf(fmaxf(v.x, 0.f), 1.f);
        float gg = fminf(fmaxf(v.y, 0.f), 1.f);
        float bb = fminf(fmaxf(v.z, 0.f), 1.f);
        ldsYf[r * YSTR + c] = 0.299f * rr + 0.587f * gg + 0.114f * bb;
    }
    __syncthreads();

    // ---- C: f16 pair table: entry[r][c] = (y(c), y(c+1)) ----
    for (int e = tid; e < XD * XD; e += 256) {   // 46x46 entries
        int r = e / XD, c = e - r * XD;
        h2 p;
        p.x = (_Float16)ldsYf[r * YSTR + c];
        p.y = (_Float16)ldsYf[r * YSTR + c + 1];
        ldsY2[r * YSTR + c] = __builtin_bit_cast(unsigned, p);
    }
    __syncthreads();

    // ---- D: row-norm H(r,c) = sum_{d=0..4} yh(r,c+d)^2 ----
    for (int e = tid; e < XD * 42; e += 256) {
        int r = e / 42, c = e - r * 42;
        h2 a  = __builtin_bit_cast(h2, ldsY2[r * YSTR + c]);
        h2 b  = __builtin_bit_cast(h2, ldsY2[r * YSTR + c + 2]);
        h2 cc = __builtin_bit_cast(h2, ldsY2[r * YSTR + c + 4]);
        float x0 = (float)a.x, x1 = (float)a.y;
        float x2 = (float)b.x, x3 = (float)b.y;
        float x4 = (float)cc.x;
        ldsH[r * HSTR + c] = x0*x0 + x1*x1 + x2*x2 + x3*x3 + x4*x4;
    }
    __syncthreads();

    // ---- E: V(r,c) = K2 * sum_{t=0..4} H(r+t,c) ----
    for (int e = tid; e < 42 * 42; e += 256) {
        int r = e / 42, c = e - r * 42;
        const float* hp = &ldsH[r * HSTR + c];
        float s = ((hp[0] + hp[HSTR]) + (hp[2*HSTR] + hp[3*HSTR])) + hp[4*HSTR];
        ldsV[r * VSTR + c] = K2C * s;
    }
    __syncthreads();

    const int jl = tx + HALO;          // LDS col of this thread's column
    const int il = ty * 4 + HALO;      // LDS row of first of 4 outputs

    // center patch as f16 pairs + K2-prescaled center patch norms Vc
    h2 cyP[8][3];
    float Vc[4];
    {
        float hcv[8];
        #pragma unroll
        for (int t = 0; t < 8; ++t) {
            int base = (il - 2 + t) * YSTR + (jl - 2);
            cyP[t][0] = __builtin_bit_cast(h2, ldsY2[base]);
            cyP[t][1] = __builtin_bit_cast(h2, ldsY2[base + 2]);
            h2 z = __builtin_bit_cast(h2, ldsY2[base + 4]);
            z.y = (_Float16)0.f;
            cyP[t][2] = z;
            hcv[t] = ldsH[(il - 2 + t) * HSTR + (jl - 2)];
        }
        float v0 = ((hcv[0] + hcv[1]) + (hcv[2] + hcv[3])) + hcv[4];
        float v1 = v0 - hcv[0] + hcv[5];
        float v2 = v1 - hcv[1] + hcv[6];
        float v3 = v2 - hcv[2] + hcv[7];
        Vc[0] = K2C * v0; Vc[1] = K2C * v1; Vc[2] = K2C * v2; Vc[3] = K2C * v3;
    }

    float den[4]  = {0.f, 0.f, 0.f, 0.f};
    float num0[4] = {0.f, 0.f, 0.f, 0.f};
    float num1[4] = {0.f, 0.f, 0.f, 0.f};
    float num2[4] = {0.f, 0.f, 0.f, 0.f};

    #pragma unroll 1
    for (int xs = -5; xs <= 5; ++xs) {
        const int jc  = jl - xs - 2;   // shifted 5-window base col
        const int xjc = jl - xs;       // shifted x neighbor col (ldsX)

        h2     swP[8][3];              // shifted-y f16-pair ring over rows
        float  Wr[4];                  // V-table ring (vertical norm sums)
        float4 xw[4];                  // x-neighbor ring

        #pragma unroll
        for (int t = 0; t < 8; ++t) {
            int base = (il - 7 + t) * YSTR + jc;
            swP[t][0] = __builtin_bit_cast(h2, ldsY2[base]);
            swP[t][1] = __builtin_bit_cast(h2, ldsY2[base + 2]);
            swP[t][2] = __builtin_bit_cast(h2, ldsY2[base + 4]);
        }
        #pragma unroll
        for (int t = 0; t < 4; ++t) {
            Wr[t] = ldsV[(il - 7 + t) * VSTR + jc];
            xw[t] = ldsX[(il - 5 + t) * XD + xjc];
        }

        #pragma unroll
        for (int k = 0; k <= 10; ++k) {     // ys = 5 - k
            // prefetch next step's ring entries
            h2 nsw0, nsw1, nsw2; float nWv; float4 nxw;
            if (k < 10) {
                const int nr = il + k + 1;
                int base = nr * YSTR + jc;
                nsw0 = __builtin_bit_cast(h2, ldsY2[base]);
                nsw1 = __builtin_bit_cast(h2, ldsY2[base + 2]);
                nsw2 = __builtin_bit_cast(h2, ldsY2[base + 4]);
                nWv  = ldsV[(il + k - 3) * VSTR + jc];
                nxw  = ldsX[(il + k - 1) * XD + xjc];
            }

            // row-dot cross terms (f16 MACs, f32 accumulate)
            float s[8];
            #pragma unroll
            for (int t = 0; t < 8; ++t) {
                const int m = (t + k) & 7;
                s[t] = fdot2(cyP[t][0], swP[m][0],
                       fdot2(cyP[t][1], swP[m][1],
                       fdot2(cyP[t][2], swP[m][2], 0.f)));
            }

            // sliding 5-row sums of cross terms
            float S0 = ((s[0] + s[1]) + (s[2] + s[3])) + s[4];
            float S1 = S0 - s[0] + s[5];
            float S2 = S1 - s[1] + s[6];
            float S3 = S2 - s[2] + s[7];

            float d2a[4];
            d2a[0] = fmaf(N2K2, S0, Vc[0] + Wr[k & 3]);
            d2a[1] = fmaf(N2K2, S1, Vc[1] + Wr[(k + 1) & 3]);
            d2a[2] = fmaf(N2K2, S2, Vc[2] + Wr[(k + 2) & 3]);
            d2a[3] = fmaf(N2K2, S3, Vc[3] + Wr[(k + 3) & 3]);

            #pragma unroll
            for (int o = 0; o < 4; ++o) {
                float sd = __builtin_amdgcn_sqrtf(__builtin_fabsf(d2a[o]));
                float w  = fast_exp2(-sd);
                float4 xv = xw[(k + o) & 3];
                num0[o] = fmaf(w, xv.x, num0[o]);
                num1[o] = fmaf(w, xv.y, num1[o]);
                num2[o] = fmaf(w, xv.z, num2[o]);
                den[o] += w;
            }

            // commit prefetched ring entries
            if (k < 10) {
                swP[k & 7][0] = nsw0;
                swP[k & 7][1] = nsw1;
                swP[k & 7][2] = nsw2;
                Wr[k & 3] = nWv;
                xw[k & 3] = nxw;
            }
        }
    }

    // ---- epilogue ----
    float* ob = out + (size_t)n * 3 * HWSZ;
    #pragma unroll
    for (int o = 0; o < 4; ++o) {
        int gi = ti + ty * 4 + o;
        int gj = tj + tx;
        size_t off = (size_t)gi * W_IMG + gj;
        float inv = __builtin_amdgcn_rcpf(den[o]);
        float v0 = fminf(fmaxf(num0[o] * inv, 0.f), 1.f);
        float v1 = fminf(fmaxf(num1[o] * inv, 0.f), 1.f);
        float v2 = fminf(fmaxf(num2[o] * inv, 0.f), 1.f);
        ob[off]            = v0;
        ob[off + HWSZ]     = v1;
        ob[off + 2 * HWSZ] = v2;
    }
}

extern "C" void kernel_launch(void* const* d_in, const int* in_sizes, int n_in,
                              void* d_out, int out_size, void* d_ws, size_t ws_size,
                              hipStream_t stream) {
    const float* x = (const float*)d_in[0];
    float* out = (float*)d_out;
    dim3 grid(W_IMG / TILE, H_IMG / TILE, 2);   // (16,16,2) = 512 blocks
    dim3 block(32, 8);
    nlm_kernel<<<grid, block, 0, stream>>>(x, out);
}